// Round 3
// baseline (8778.904 us; speedup 1.0000x reference)
//
#include <hip/hip_runtime.h>
#include <math.h>

#define BATCH 32
#define TLEN  4096
#define DIM   64
#define NHASH 8
#define NBUCK 64   // n_buckets
#define BSIZE 64   // bucket size

// ---------------------------------------------------------------------------
// Hash kernel: colors[b,r,t] = argmax_n( concat(px, -px) ), px_n = x[b,t,:].proj[:,r,n]
// f64 accumulation so argmax decisions match the high-precision reference.
// One thread per t; proj[:,r,:] staged in LDS as f64 (broadcast reads);
// x row cached in 64 f64 registers.
// ---------------------------------------------------------------------------
__global__ __launch_bounds__(256, 2)
void hash_kernel(const float* __restrict__ x, const float* __restrict__ proj,
                 int* __restrict__ buckets) {
  __shared__ double ps[64][66];  // ps[n][d]; stride 66 doubles (528B, 16B-aligned)
  const int tid = threadIdx.x;
  const int r = blockIdx.y, b = blockIdx.z;
  const int t0 = blockIdx.x << 8;

  // stage proj[d, r, n] -> ps[n][d]   (proj flat: d*512 + r*64 + n)
  for (int kk = 0; kk < 16; ++kk) {
    int idx = (kk << 8) + tid;        // 4096 = 64d x 64n
    int d = idx >> 6, n = idx & 63;
    ps[n][d] = (double)proj[d * 512 + r * 64 + n];
  }
  __syncthreads();

  const int t = t0 + tid;
  const float* xr = x + ((size_t)b * TLEN + t) * DIM;
  double xd[64];
#pragma unroll
  for (int g = 0; g < 16; ++g) {
    float4 vv = ((const float4*)xr)[g];
    xd[4 * g + 0] = (double)vv.x; xd[4 * g + 1] = (double)vv.y;
    xd[4 * g + 2] = (double)vv.z; xd[4 * g + 3] = (double)vv.w;
  }

  double bestp = -1e300, bestn = -1e300;
  int idxp = 0, idxn = 0;
  for (int n = 0; n < 64; ++n) {
    double a0 = 0.0, a1 = 0.0, a2 = 0.0, a3 = 0.0;
#pragma unroll
    for (int d = 0; d < 64; d += 4) {
      a0 = fma(xd[d + 0], ps[n][d + 0], a0);
      a1 = fma(xd[d + 1], ps[n][d + 1], a1);
      a2 = fma(xd[d + 2], ps[n][d + 2], a2);
      a3 = fma(xd[d + 3], ps[n][d + 3], a3);
    }
    double acc = (a0 + a1) + (a2 + a3);
    // strict > keeps FIRST occurrence of max (jnp.argmax semantics)
    if (acc > bestp)  { bestp = acc;  idxp = n; }
    if (-acc > bestn) { bestn = -acc; idxn = n; }
  }
  // on exact cross-half tie the positive half (smaller index) wins
  buckets[((size_t)b * NHASH + r) * TLEN + t] = (bestp >= bestn) ? idxp : (idxn + 64);
}

// ---------------------------------------------------------------------------
// Stable counting sort per (b,r): sticker[i] = index of i-th element in
// stable ascending sort by bucket id (== jnp.argsort, stable).
// Also emits inverse permutation pos[e] = sorted position of e (if pos!=null).
// One wave; lane owns contiguous chunk of 64 elements.
// ---------------------------------------------------------------------------
__global__ __launch_bounds__(64)
void sort_kernel(const int* __restrict__ buckets, int* __restrict__ sticker,
                 int* __restrict__ pos) {
  __shared__ int lhist[64][129];   // [chunk][bin], +1 pad breaks bank aliasing
  __shared__ int starts[128];
  const int lane = threadIdx.x;
  const int br = blockIdx.x;       // b*NHASH + r
  const int* bk = buckets + (size_t)br * TLEN;
  int* st = sticker + (size_t)br * TLEN;
  int* ps = pos ? pos + (size_t)br * TLEN : nullptr;

  for (int i = 0; i < 128; ++i) lhist[lane][i] = 0;
  __syncthreads();
  for (int i = 0; i < 64; ++i) {
    int bb = bk[lane * 64 + i];
    lhist[lane][bb]++;
  }
  __syncthreads();

  // column-wise exclusive prefix over chunks; lane owns bins {lane, lane+64}
  int tot0 = 0, tot1 = 0;
  for (int c = 0; c < 64; ++c) {
    int v0 = lhist[c][lane];      lhist[c][lane]      = tot0; tot0 += v0;
    int v1 = lhist[c][lane + 64]; lhist[c][lane + 64] = tot1; tot1 += v1;
  }
  // exclusive scan across the 128 bin totals (bins ordered lane, then lane+64)
  int s0 = tot0;
  for (int off = 1; off < 64; off <<= 1) {
    int u = __shfl_up(s0, off, 64);
    if (lane >= off) s0 += u;
  }
  int total0 = __shfl(s0, 63, 64);
  int s1 = tot1;
  for (int off = 1; off < 64; off <<= 1) {
    int u = __shfl_up(s1, off, 64);
    if (lane >= off) s1 += u;
  }
  starts[lane] = s0 - tot0;
  starts[lane + 64] = s1 - tot1 + total0;
  __syncthreads();

  // stable scatter: walk own chunk in order
  for (int i = 0; i < 64; ++i) {
    int e = lane * 64 + i;
    int bb = bk[e];
    int c = lhist[lane][bb];
    lhist[lane][bb] = c + 1;
    int sp = starts[bb] + c;
    st[sp] = e;
    if (ps) ps[e] = sp;
  }
}

// ---------------------------------------------------------------------------
// Blocked attention per (b_local, r, bucket n): 64 queries x 128 keys
// (prev+cur bucket), f32 vector math. Output written in SORTED order
// (fully coalesced contiguous 16 KB per block); undo-sort happens on the
// read side in combine_kernel. K/V staged in XOR-swizzled LDS (64 KB).
// Thread map: row = tid>>2 (0..63), part = tid&3 owns j = part + 4*jj.
// ---------------------------------------------------------------------------
__global__ __launch_bounds__(256, 2)
void attn_kernel(const float* __restrict__ q, const float* __restrict__ k,
                 const float* __restrict__ v,
                 const int* __restrict__ sticker_q, const int* __restrict__ sticker_k,
                 float* __restrict__ so_buf, float* __restrict__ slse_buf,
                 int b_off) {
  __shared__ float Ks[128 * 64];   // 32 KB
  __shared__ float Vs[128 * 64];   // 32 KB  (total exactly 64 KB)

  const int tid = threadIdx.x;
  const int n = blockIdx.x, r = blockIdx.y, bl = blockIdx.z;
  const int b = b_off + bl;
  const size_t brbase = ((size_t)b * NHASH + r) * TLEN;       // global (stickers/lse)
  const size_t obase  = ((size_t)bl * NHASH + r) * TLEN;      // chunk-local (so_buf)
  const int nprev = (n + NBUCK - 1) & (NBUCK - 1);

  const float* kb = k + (size_t)b * TLEN * DIM;
  const float* vb = v + (size_t)b * TLEN * DIM;
  const float* qb = q + (size_t)b * TLEN * DIM;

  // stage K,V swizzled: element (row, g) stored at (row, g ^ (row&15)) in 16B granules
  for (int it = 0; it < 8; ++it) {
    int idx = it * 256 + tid;          // 2048 = 128 rows x 16 granules
    int row = idx >> 4, g = idx & 15;
    int srow = (row < 64) ? (nprev * 64 + row) : (n * 64 + (row - 64));
    int ik = sticker_k[brbase + srow];
    float4 kv = *(const float4*)(kb + (size_t)ik * DIM + g * 4);
    *(float4*)&Ks[row * 64 + ((g ^ (row & 15)) << 2)] = kv;
    float4 vv = *(const float4*)(vb + (size_t)ik * DIM + g * 4);
    *(float4*)&Vs[row * 64 + ((g ^ (row & 15)) << 2)] = vv;
  }

  const int row = tid >> 2, part = tid & 3;
  const int torig = sticker_q[brbase + n * 64 + row];
  // Q row straight from global to registers (quad-redundant, L1-served)
  float4 qreg[16];
#pragma unroll
  for (int g = 0; g < 16; ++g)
    qreg[g] = *(const float4*)(qb + (size_t)torig * DIM + g * 4);
  __syncthreads();

  // dots for j = part + 4*jj
  float p[32];
#pragma unroll
  for (int jj = 0; jj < 32; ++jj) {
    int j = part + (jj << 2);
    int js = j & 15;
    float a0 = 0.f, a1 = 0.f, a2 = 0.f, a3 = 0.f;
#pragma unroll
    for (int g = 0; g < 16; ++g) {
      float4 kv = *(const float4*)&Ks[j * 64 + ((g ^ js) << 2)];
      a0 = fmaf(qreg[g].x, kv.x, a0);
      a1 = fmaf(qreg[g].y, kv.y, a1);
      a2 = fmaf(qreg[g].z, kv.z, a2);
      a3 = fmaf(qreg[g].w, kv.w, a3);
    }
    p[jj] = ((a0 + a1) + (a2 + a3)) * 0.125f;   // d^-0.5 = 1/8
  }

  // softmax over the 128 j's (32 local + quad shuffle)
  float m = -INFINITY;
#pragma unroll
  for (int jj = 0; jj < 32; ++jj) m = fmaxf(m, p[jj]);
  m = fmaxf(m, __shfl_xor(m, 1, 64));
  m = fmaxf(m, __shfl_xor(m, 2, 64));
  float Z = 0.f;
#pragma unroll
  for (int jj = 0; jj < 32; ++jj) { p[jj] = __expf(p[jj] - m); Z += p[jj]; }
  Z += __shfl_xor(Z, 1, 64);
  Z += __shfl_xor(Z, 2, 64);
  const float invZ = 1.0f / Z;
  const float lse = m + __logf(Z);

  // PV: acc[g] = sum_j (p_j/Z) * V[j][4g..4g+3]
  float4 acc[16];
#pragma unroll
  for (int g = 0; g < 16; ++g) acc[g] = make_float4(0.f, 0.f, 0.f, 0.f);
#pragma unroll
  for (int jj = 0; jj < 32; ++jj) {
    int j = part + (jj << 2);
    int js = j & 15;
    float pw = p[jj] * invZ;
#pragma unroll
    for (int g = 0; g < 16; ++g) {
      float4 vv = *(const float4*)&Vs[j * 64 + ((g ^ js) << 2)];
      acc[g].x = fmaf(pw, vv.x, acc[g].x);
      acc[g].y = fmaf(pw, vv.y, acc[g].y);
      acc[g].z = fmaf(pw, vv.z, acc[g].z);
      acc[g].w = fmaf(pw, vv.w, acc[g].w);
    }
  }
  // combine partial sums across the quad (parts hold disjoint j sets)
#pragma unroll
  for (int g = 0; g < 16; ++g) {
    acc[g].x += __shfl_xor(acc[g].x, 1, 64);
    acc[g].y += __shfl_xor(acc[g].y, 1, 64);
    acc[g].z += __shfl_xor(acc[g].z, 1, 64);
    acc[g].w += __shfl_xor(acc[g].w, 1, 64);
  }
#pragma unroll
  for (int g = 0; g < 16; ++g) {
    acc[g].x += __shfl_xor(acc[g].x, 2, 64);
    acc[g].y += __shfl_xor(acc[g].y, 2, 64);
    acc[g].z += __shfl_xor(acc[g].z, 2, 64);
    acc[g].w += __shfl_xor(acc[g].w, 2, 64);
  }

  // write in SORTED order: contiguous, fully coalesced. part p writes g in [4p,4p+4)
  float* orow = so_buf + (obase + (size_t)(n * 64 + row)) * DIM;
#pragma unroll
  for (int gg = 0; gg < 4; ++gg) {
    int g = part * 4 + gg;
    *(float4*)(orow + g * 4) = acc[g];
  }
  if (part == 0) slse_buf[brbase + n * 64 + row] = lse;
}

// ---------------------------------------------------------------------------
// Combine the 8 hash rounds: softmax over per-(b,t) lse, weighted sum of o.
// Undo-sort fused here as a GATHER: row for round r is pos_q[b,r,t] in the
// sorted buffers. Thread per (b,t,g) float4 chunk.
// ---------------------------------------------------------------------------
__global__ __launch_bounds__(256)
void combine_kernel(const float* __restrict__ so_buf, const float* __restrict__ slse_buf,
                    const int* __restrict__ pos_q, float* __restrict__ out, int b_off) {
  const size_t tid = (size_t)blockIdx.x * 256 + threadIdx.x;  // CB*T*16
  const size_t bt = tid >> 4;
  const int g = (int)(tid & 15);
  const size_t bl = bt >> 12;       // local batch (T = 4096)
  const size_t t = bt & 4095;
  const size_t b = b_off + bl;

  int pp[8];
  float l[8];
  float M = -INFINITY;
#pragma unroll
  for (int rr = 0; rr < 8; ++rr) {
    pp[rr] = pos_q[(b * NHASH + rr) * TLEN + t];
    l[rr] = slse_buf[(b * NHASH + rr) * TLEN + pp[rr]];
    M = fmaxf(M, l[rr]);
  }
  float Z = 0.f;
  float w[8];
#pragma unroll
  for (int rr = 0; rr < 8; ++rr) { w[rr] = __expf(l[rr] - M); Z += w[rr]; }
  const float invZ = 1.0f / Z;

  float4 s = make_float4(0.f, 0.f, 0.f, 0.f);
#pragma unroll
  for (int rr = 0; rr < 8; ++rr) {
    const float* op = so_buf + ((bl * NHASH + rr) * TLEN + (size_t)pp[rr]) * DIM + g * 4;
    float4 ov = *(const float4*)op;
    s.x = fmaf(w[rr], ov.x, s.x);
    s.y = fmaf(w[rr], ov.y, s.y);
    s.z = fmaf(w[rr], ov.z, s.z);
    s.w = fmaf(w[rr], ov.w, s.w);
  }
  s.x *= invZ; s.y *= invZ; s.z *= invZ; s.w *= invZ;
  *(float4*)(out + (b * TLEN + t) * DIM + g * 4) = s;
}

// ---------------------------------------------------------------------------
// Workspace layout (adaptive to ws_size):
//   [0,  4MB)  sticker_q
//   [4,  8MB)  sticker_k
//   [8, 12MB)  pos_q      (inverse permutation of sticker_q)
//   [12,16MB)  slse_buf   (lse in sorted order)
//   [16MB, ..) shared region:
//       during hash/sort:  buckets_q (4MB) + buckets_k (4MB)
//       during attn/combine: so_buf, CB*8MB  (CB = batches per chunk)
// Minimum footprint: 24 MB (CB=1). CB chosen largest power of 2 that fits.
// ---------------------------------------------------------------------------
extern "C" void kernel_launch(void* const* d_in, const int* in_sizes, int n_in,
                              void* d_out, int out_size, void* d_ws, size_t ws_size,
                              hipStream_t stream) {
  const float* q = (const float*)d_in[0];
  const float* k = (const float*)d_in[1];
  const float* v = (const float*)d_in[2];
  const float* proj = (const float*)d_in[3];
  float* out = (float*)d_out;

  char* ws = (char*)d_ws;
  const size_t MB = (size_t)1 << 20;
  int* sticker_q = (int*)(ws + 0 * MB);
  int* sticker_k = (int*)(ws + 4 * MB);
  int* pos_q     = (int*)(ws + 8 * MB);
  float* slse_buf = (float*)(ws + 12 * MB);
  int* buckets_q = (int*)(ws + 16 * MB);
  int* buckets_k = (int*)(ws + 20 * MB);
  float* so_buf  = (float*)(ws + 16 * MB);  // reuses buckets region after sorts

  // pick chunk size (batches per attn/combine pass) that fits the workspace
  int CB = 32;
  while (CB > 1 && 16 * MB + (size_t)CB * 8 * MB > ws_size) CB >>= 1;

  hash_kernel<<<dim3(TLEN / 256, NHASH, BATCH), 256, 0, stream>>>(q, proj, buckets_q);
  hash_kernel<<<dim3(TLEN / 256, NHASH, BATCH), 256, 0, stream>>>(k, proj, buckets_k);
  sort_kernel<<<dim3(BATCH * NHASH), 64, 0, stream>>>(buckets_q, sticker_q, pos_q);
  sort_kernel<<<dim3(BATCH * NHASH), 64, 0, stream>>>(buckets_k, sticker_k, nullptr);

  for (int b_off = 0; b_off < BATCH; b_off += CB) {
    attn_kernel<<<dim3(NBUCK, NHASH, CB), 256, 0, stream>>>(
        q, k, v, sticker_q, sticker_k, so_buf, slse_buf, b_off);
    combine_kernel<<<dim3(CB * TLEN * 16 / 256), 256, 0, stream>>>(
        so_buf, slse_buf, pos_q, out, b_off);
  }
}

// Round 4
// 1511.295 us; speedup vs baseline: 5.8089x; 5.8089x over previous
//
#include <hip/hip_runtime.h>
#include <math.h>

#define BATCH 32
#define TLEN  4096
#define DIM   64
#define NHASH 8
#define NBUCK 64   // n_buckets
#define BSIZE 64   // bucket size

// ---------------------------------------------------------------------------
// Hash kernel: colors[b,r,t] = argmax_n( concat(px, -px) ), px_n = x[b,t,:].proj[:,r,n]
// f64 accumulation so argmax decisions match the high-precision reference.
// One thread per t; proj[:,r,:] staged in LDS as f64 (broadcast reads);
// x row cached in 64 f64 registers.
// ---------------------------------------------------------------------------
__global__ __launch_bounds__(256, 2)
void hash_kernel(const float* __restrict__ x, const float* __restrict__ proj,
                 int* __restrict__ buckets) {
  __shared__ double ps[64][66];  // ps[n][d]; stride 66 doubles (528B, 16B-aligned)
  const int tid = threadIdx.x;
  const int r = blockIdx.y, b = blockIdx.z;
  const int t0 = blockIdx.x << 8;

  // stage proj[d, r, n] -> ps[n][d]   (proj flat: d*512 + r*64 + n)
  for (int kk = 0; kk < 16; ++kk) {
    int idx = (kk << 8) + tid;        // 4096 = 64d x 64n
    int d = idx >> 6, n = idx & 63;
    ps[n][d] = (double)proj[d * 512 + r * 64 + n];
  }
  __syncthreads();

  const int t = t0 + tid;
  const float* xr = x + ((size_t)b * TLEN + t) * DIM;
  double xd[64];
#pragma unroll
  for (int g = 0; g < 16; ++g) {
    float4 vv = ((const float4*)xr)[g];
    xd[4 * g + 0] = (double)vv.x; xd[4 * g + 1] = (double)vv.y;
    xd[4 * g + 2] = (double)vv.z; xd[4 * g + 3] = (double)vv.w;
  }

  double bestp = -1e300, bestn = -1e300;
  int idxp = 0, idxn = 0;
  for (int n = 0; n < 64; ++n) {
    double a0 = 0.0, a1 = 0.0, a2 = 0.0, a3 = 0.0;
#pragma unroll
    for (int d = 0; d < 64; d += 4) {
      a0 = fma(xd[d + 0], ps[n][d + 0], a0);
      a1 = fma(xd[d + 1], ps[n][d + 1], a1);
      a2 = fma(xd[d + 2], ps[n][d + 2], a2);
      a3 = fma(xd[d + 3], ps[n][d + 3], a3);
    }
    double acc = (a0 + a1) + (a2 + a3);
    // strict > keeps FIRST occurrence of max (jnp.argmax semantics)
    if (acc > bestp)  { bestp = acc;  idxp = n; }
    if (-acc > bestn) { bestn = -acc; idxn = n; }
  }
  // on exact cross-half tie the positive half (smaller index) wins
  buckets[((size_t)b * NHASH + r) * TLEN + t] = (bestp >= bestn) ? idxp : (idxn + 64);
}

// ---------------------------------------------------------------------------
// Stable counting sort per (b,r): sticker[i] = index of i-th element in
// stable ascending sort by bucket id (== jnp.argsort, stable).
// Also emits inverse permutation pos[e] = sorted position of e (if pos!=null).
// One wave; lane owns contiguous chunk of 64 elements.
// ---------------------------------------------------------------------------
__global__ __launch_bounds__(64)
void sort_kernel(const int* __restrict__ buckets, int* __restrict__ sticker,
                 int* __restrict__ pos) {
  __shared__ int lhist[64][129];   // [chunk][bin], +1 pad breaks bank aliasing
  __shared__ int starts[128];
  const int lane = threadIdx.x;
  const int br = blockIdx.x;       // b*NHASH + r
  const int* bk = buckets + (size_t)br * TLEN;
  int* st = sticker + (size_t)br * TLEN;
  int* ps = pos ? pos + (size_t)br * TLEN : nullptr;

  for (int i = 0; i < 128; ++i) lhist[lane][i] = 0;
  __syncthreads();
  for (int i = 0; i < 64; ++i) {
    int bb = bk[lane * 64 + i];
    lhist[lane][bb]++;
  }
  __syncthreads();

  // column-wise exclusive prefix over chunks; lane owns bins {lane, lane+64}
  int tot0 = 0, tot1 = 0;
  for (int c = 0; c < 64; ++c) {
    int v0 = lhist[c][lane];      lhist[c][lane]      = tot0; tot0 += v0;
    int v1 = lhist[c][lane + 64]; lhist[c][lane + 64] = tot1; tot1 += v1;
  }
  // exclusive scan across the 128 bin totals (bins ordered lane, then lane+64)
  int s0 = tot0;
  for (int off = 1; off < 64; off <<= 1) {
    int u = __shfl_up(s0, off, 64);
    if (lane >= off) s0 += u;
  }
  int total0 = __shfl(s0, 63, 64);
  int s1 = tot1;
  for (int off = 1; off < 64; off <<= 1) {
    int u = __shfl_up(s1, off, 64);
    if (lane >= off) s1 += u;
  }
  starts[lane] = s0 - tot0;
  starts[lane + 64] = s1 - tot1 + total0;
  __syncthreads();

  // stable scatter: walk own chunk in order
  for (int i = 0; i < 64; ++i) {
    int e = lane * 64 + i;
    int bb = bk[e];
    int c = lhist[lane][bb];
    lhist[lane][bb] = c + 1;
    int sp = starts[bb] + c;
    st[sp] = e;
    if (ps) ps[e] = sp;
  }
}

// ---------------------------------------------------------------------------
// Blocked attention per (b_local, r, bucket n): 64 queries x 128 keys
// (prev+cur bucket), f32 vector math. Output written in SORTED order
// (coalesced); undo-sort happens on the read side in combine_kernel.
// K/V staged in XOR-swizzled LDS (64 KB).
// Thread map: row = tid>>2 (0..63), part = tid&3 owns j = part + 4*jj.
// NOTE: every private-array index must be compile-time constant — a runtime
// index (e.g. acc[part*4+gg]) forces the array into scratch and generates
// gigabytes of spill traffic (round-3 post-mortem: 7.2 GB WRITE_SIZE).
// ---------------------------------------------------------------------------
__global__ __launch_bounds__(256, 2)
void attn_kernel(const float* __restrict__ q, const float* __restrict__ k,
                 const float* __restrict__ v,
                 const int* __restrict__ sticker_q, const int* __restrict__ sticker_k,
                 float* __restrict__ so_buf, float* __restrict__ slse_buf,
                 int b_off) {
  __shared__ float Ks[128 * 64];   // 32 KB
  __shared__ float Vs[128 * 64];   // 32 KB  (total exactly 64 KB)

  const int tid = threadIdx.x;
  const int n = blockIdx.x, r = blockIdx.y, bl = blockIdx.z;
  const int b = b_off + bl;
  const size_t brbase = ((size_t)b * NHASH + r) * TLEN;       // global (stickers/lse)
  const size_t obase  = ((size_t)bl * NHASH + r) * TLEN;      // chunk-local (so_buf)
  const int nprev = (n + NBUCK - 1) & (NBUCK - 1);

  const float* kb = k + (size_t)b * TLEN * DIM;
  const float* vb = v + (size_t)b * TLEN * DIM;
  const float* qb = q + (size_t)b * TLEN * DIM;

  // stage K,V swizzled: element (row, g) stored at (row, g ^ (row&15)) in 16B granules
  for (int it = 0; it < 8; ++it) {
    int idx = it * 256 + tid;          // 2048 = 128 rows x 16 granules
    int row = idx >> 4, g = idx & 15;
    int srow = (row < 64) ? (nprev * 64 + row) : (n * 64 + (row - 64));
    int ik = sticker_k[brbase + srow];
    float4 kv = *(const float4*)(kb + (size_t)ik * DIM + g * 4);
    *(float4*)&Ks[row * 64 + ((g ^ (row & 15)) << 2)] = kv;
    float4 vv = *(const float4*)(vb + (size_t)ik * DIM + g * 4);
    *(float4*)&Vs[row * 64 + ((g ^ (row & 15)) << 2)] = vv;
  }

  const int row = tid >> 2, part = tid & 3;
  const int torig = sticker_q[brbase + n * 64 + row];
  // Q row straight from global to registers (quad-redundant, L1-served)
  float4 qreg[16];
#pragma unroll
  for (int g = 0; g < 16; ++g)
    qreg[g] = *(const float4*)(qb + (size_t)torig * DIM + g * 4);
  __syncthreads();

  // dots for j = part + 4*jj
  float p[32];
#pragma unroll
  for (int jj = 0; jj < 32; ++jj) {
    int j = part + (jj << 2);
    int js = j & 15;
    float a0 = 0.f, a1 = 0.f, a2 = 0.f, a3 = 0.f;
#pragma unroll
    for (int g = 0; g < 16; ++g) {
      float4 kv = *(const float4*)&Ks[j * 64 + ((g ^ js) << 2)];
      a0 = fmaf(qreg[g].x, kv.x, a0);
      a1 = fmaf(qreg[g].y, kv.y, a1);
      a2 = fmaf(qreg[g].z, kv.z, a2);
      a3 = fmaf(qreg[g].w, kv.w, a3);
    }
    p[jj] = ((a0 + a1) + (a2 + a3)) * 0.125f;   // d^-0.5 = 1/8
  }

  // softmax over the 128 j's (32 local + quad shuffle)
  float m = -INFINITY;
#pragma unroll
  for (int jj = 0; jj < 32; ++jj) m = fmaxf(m, p[jj]);
  m = fmaxf(m, __shfl_xor(m, 1, 64));
  m = fmaxf(m, __shfl_xor(m, 2, 64));
  float Z = 0.f;
#pragma unroll
  for (int jj = 0; jj < 32; ++jj) { p[jj] = __expf(p[jj] - m); Z += p[jj]; }
  Z += __shfl_xor(Z, 1, 64);
  Z += __shfl_xor(Z, 2, 64);
  const float invZ = 1.0f / Z;
  const float lse = m + __logf(Z);

  // PV: acc[g] = sum_j (p_j/Z) * V[j][4g..4g+3]
  float4 acc[16];
#pragma unroll
  for (int g = 0; g < 16; ++g) acc[g] = make_float4(0.f, 0.f, 0.f, 0.f);
#pragma unroll
  for (int jj = 0; jj < 32; ++jj) {
    int j = part + (jj << 2);
    int js = j & 15;
    float pw = p[jj] * invZ;
#pragma unroll
    for (int g = 0; g < 16; ++g) {
      float4 vv = *(const float4*)&Vs[j * 64 + ((g ^ js) << 2)];
      acc[g].x = fmaf(pw, vv.x, acc[g].x);
      acc[g].y = fmaf(pw, vv.y, acc[g].y);
      acc[g].z = fmaf(pw, vv.z, acc[g].z);
      acc[g].w = fmaf(pw, vv.w, acc[g].w);
    }
  }
  // combine partial sums across the quad (parts hold disjoint j sets)
#pragma unroll
  for (int g = 0; g < 16; ++g) {
    acc[g].x += __shfl_xor(acc[g].x, 1, 64);
    acc[g].y += __shfl_xor(acc[g].y, 1, 64);
    acc[g].z += __shfl_xor(acc[g].z, 1, 64);
    acc[g].w += __shfl_xor(acc[g].w, 1, 64);
  }
#pragma unroll
  for (int g = 0; g < 16; ++g) {
    acc[g].x += __shfl_xor(acc[g].x, 2, 64);
    acc[g].y += __shfl_xor(acc[g].y, 2, 64);
    acc[g].z += __shfl_xor(acc[g].z, 2, 64);
    acc[g].w += __shfl_xor(acc[g].w, 2, 64);
  }

  // write in SORTED order, contiguous. All parts now hold the full sum;
  // part p writes quarter p via STATICALLY-indexed predicated stores
  // (no runtime index into acc[] -> acc stays in registers, no scratch).
  float* orow = so_buf + (obase + (size_t)(n * 64 + row)) * DIM;
#pragma unroll
  for (int g = 0; g < 16; ++g) {
    if ((g >> 2) == part) {
      *(float4*)(orow + g * 4) = acc[g];
    }
  }
  if (part == 0) slse_buf[brbase + n * 64 + row] = lse;
}

// ---------------------------------------------------------------------------
// Combine the 8 hash rounds: softmax over per-(b,t) lse, weighted sum of o.
// Undo-sort fused here as a GATHER: row for round r is pos_q[b,r,t] in the
// sorted buffers. Thread per (b,t,g) float4 chunk.
// ---------------------------------------------------------------------------
__global__ __launch_bounds__(256)
void combine_kernel(const float* __restrict__ so_buf, const float* __restrict__ slse_buf,
                    const int* __restrict__ pos_q, float* __restrict__ out, int b_off) {
  const size_t tid = (size_t)blockIdx.x * 256 + threadIdx.x;  // CB*T*16
  const size_t bt = tid >> 4;
  const int g = (int)(tid & 15);
  const size_t bl = bt >> 12;       // local batch (T = 4096)
  const size_t t = bt & 4095;
  const size_t b = b_off + bl;

  int pp[8];
  float l[8];
  float M = -INFINITY;
#pragma unroll
  for (int rr = 0; rr < 8; ++rr) {
    pp[rr] = pos_q[(b * NHASH + rr) * TLEN + t];
    l[rr] = slse_buf[(b * NHASH + rr) * TLEN + pp[rr]];
    M = fmaxf(M, l[rr]);
  }
  float Z = 0.f;
  float w[8];
#pragma unroll
  for (int rr = 0; rr < 8; ++rr) { w[rr] = __expf(l[rr] - M); Z += w[rr]; }
  const float invZ = 1.0f / Z;

  float4 s = make_float4(0.f, 0.f, 0.f, 0.f);
#pragma unroll
  for (int rr = 0; rr < 8; ++rr) {
    const float* op = so_buf + ((bl * NHASH + rr) * TLEN + (size_t)pp[rr]) * DIM + g * 4;
    float4 ov = *(const float4*)op;
    s.x = fmaf(w[rr], ov.x, s.x);
    s.y = fmaf(w[rr], ov.y, s.y);
    s.z = fmaf(w[rr], ov.z, s.z);
    s.w = fmaf(w[rr], ov.w, s.w);
  }
  s.x *= invZ; s.y *= invZ; s.z *= invZ; s.w *= invZ;
  *(float4*)(out + (b * TLEN + t) * DIM + g * 4) = s;
}

// ---------------------------------------------------------------------------
// Workspace layout (adaptive to ws_size):
//   [0,  4MB)  sticker_q
//   [4,  8MB)  sticker_k
//   [8, 12MB)  pos_q      (inverse permutation of sticker_q)
//   [12,16MB)  slse_buf   (lse in sorted order)
//   [16MB, ..) shared region:
//       during hash/sort:  buckets_q (4MB) + buckets_k (4MB)
//       during attn/combine: so_buf, CB*8MB  (CB = batches per chunk)
// Minimum footprint: 24 MB (CB=1). CB chosen largest power of 2 that fits.
// ---------------------------------------------------------------------------
extern "C" void kernel_launch(void* const* d_in, const int* in_sizes, int n_in,
                              void* d_out, int out_size, void* d_ws, size_t ws_size,
                              hipStream_t stream) {
  const float* q = (const float*)d_in[0];
  const float* k = (const float*)d_in[1];
  const float* v = (const float*)d_in[2];
  const float* proj = (const float*)d_in[3];
  float* out = (float*)d_out;

  char* ws = (char*)d_ws;
  const size_t MB = (size_t)1 << 20;
  int* sticker_q = (int*)(ws + 0 * MB);
  int* sticker_k = (int*)(ws + 4 * MB);
  int* pos_q     = (int*)(ws + 8 * MB);
  float* slse_buf = (float*)(ws + 12 * MB);
  int* buckets_q = (int*)(ws + 16 * MB);
  int* buckets_k = (int*)(ws + 20 * MB);
  float* so_buf  = (float*)(ws + 16 * MB);  // reuses buckets region after sorts

  // pick chunk size (batches per attn/combine pass) that fits the workspace
  int CB = 32;
  while (CB > 1 && 16 * MB + (size_t)CB * 8 * MB > ws_size) CB >>= 1;

  hash_kernel<<<dim3(TLEN / 256, NHASH, BATCH), 256, 0, stream>>>(q, proj, buckets_q);
  hash_kernel<<<dim3(TLEN / 256, NHASH, BATCH), 256, 0, stream>>>(k, proj, buckets_k);
  sort_kernel<<<dim3(BATCH * NHASH), 64, 0, stream>>>(buckets_q, sticker_q, pos_q);
  sort_kernel<<<dim3(BATCH * NHASH), 64, 0, stream>>>(buckets_k, sticker_k, nullptr);

  for (int b_off = 0; b_off < BATCH; b_off += CB) {
    attn_kernel<<<dim3(NBUCK, NHASH, CB), 256, 0, stream>>>(
        q, k, v, sticker_q, sticker_k, so_buf, slse_buf, b_off);
    combine_kernel<<<dim3(CB * TLEN * 16 / 256), 256, 0, stream>>>(
        so_buf, slse_buf, pos_q, out, b_off);
  }
}